// Round 5
// baseline (156.980 us; speedup 1.0000x reference)
//
#include <hip/hip_runtime.h>

#define BB 2
#define NN 768
#define FF 128
#define HH 128
#define TR 32                 // tile rows
#define TC 64                 // tile cols
#define NIT (NN / TR)         // 24
#define NJT (NN / TC)         // 12
#define DELTA 0.02f
#define WCAP (1u << 20)

// k1: fused 2-layer edge-feat MLP in f64, 2 rows/block.
// Xc = X + gate*feats stored f64 (authority) + f32 (fast pass).
// Block 0: packs score-MLP weights, reduces linear-part scalars A,B,C, zeroes counter.
__global__ __launch_bounds__(256)
void edgefeat_kernel(const float* __restrict__ X,
                     const float* __restrict__ w1, const float* __restrict__ b1,
                     const float* __restrict__ w2, const float* __restrict__ b2,
                     const float* __restrict__ gatep,
                     const float* __restrict__ sm_w1, const float* __restrict__ sm_b1,
                     const float* __restrict__ sm_w2,
                     double* __restrict__ Xc64, float* __restrict__ Xc32,
                     double* __restrict__ wpack64, float* __restrict__ wpackf,
                     unsigned* __restrict__ counter) {
    __shared__ float  Xs[2][FF];
    __shared__ double Hs[2][HH + 2];
    __shared__ float  red[3][128];
    const int tid = threadIdx.x;
    const int r = tid >> 7;        // 0..1
    const int c = tid & 127;       // 0..127
    const int row0 = blockIdx.x * 2;

    if (blockIdx.x == 0 && r == 0) {
        double a  = (double)sm_w1[c];
        double bb = (double)sm_w1[HH + c];
        double be = (double)sm_b1[c];
        double wd = (double)sm_w2[2 * c + 1] - (double)sm_w2[2 * c];
        wpack64[4 * c + 0] = a;  wpack64[4 * c + 1] = bb;
        wpack64[4 * c + 2] = be; wpack64[4 * c + 3] = wd;
        wpackf[4 * c + 0] = (float)a;  wpackf[4 * c + 1] = (float)bb;
        wpackf[4 * c + 2] = (float)be; wpackf[4 * c + 3] = (float)wd;
        red[0][c] = (float)(wd * a);
        red[1][c] = (float)(wd * bb);
        red[2][c] = (float)(wd * be);
        if (c == 0) *counter = 0u;
    }

    Xs[r][c] = X[(size_t)(row0 + r) * FF + c];
    __syncthreads();

    if (blockIdx.x == 0 && tid < 64) {
        for (int s = 0; s < 3; ++s) {
            float v = red[s][tid] + red[s][tid + 64];
            for (int off = 32; off > 0; off >>= 1) v += __shfl_down(v, off, 64);
            if (tid == 0) wpackf[512 + s] = v;
        }
    }

    double acc0 = (double)b1[c], acc1 = 0.0;
#pragma unroll 8
    for (int f = 0; f < 64; ++f) {
        acc0 = fma((double)Xs[r][f],      (double)w1[f * HH + c],        acc0);
        acc1 = fma((double)Xs[r][f + 64], (double)w1[(f + 64) * HH + c], acc1);
    }
    double h1 = acc0 + acc1;
    Hs[r][c] = h1 > 0.0 ? h1 : 0.0;
    __syncthreads();

    acc0 = (double)b2[c]; acc1 = 0.0;
#pragma unroll 8
    for (int f = 0; f < 64; ++f) {
        acc0 = fma(Hs[r][f],      (double)w2[f * HH + c],        acc0);
        acc1 = fma(Hs[r][f + 64], (double)w2[(f + 64) * HH + c], acc1);
    }

    const double gate = (double)gatep[0];
    double v = (double)Xs[r][c] + gate * (acc0 + acc1);
    const int g = row0 + r;
    const int b = g / NN, i = g % NN;
    const int k = c & 1, d = c >> 1;
    size_t idx = (((size_t)(b * 2 + k)) * NN + i) * 64 + d;
    Xc64[idx] = v;
    Xc32[idx] = (float)v;
}

// k2: f32 fast pass. 32x64 tiles, 128 threads, 16 edges/thread (4x4 register block).
// MLP reduced: m = bd + gum + 0.5*(p0*A + p1*B + C) + 0.5*sum_c wd|z_c|.
__global__ __launch_bounds__(128)
void decide32_kernel(const float* __restrict__ Xc32,
                     const float* __restrict__ wpackf,
                     const float* __restrict__ sm_b2,
                     const float* __restrict__ gumbel,
                     float* __restrict__ out,
                     unsigned* __restrict__ counter,
                     unsigned* __restrict__ worklist) {
    const int I = blockIdx.x, J = blockIdx.y, b = blockIdx.z;
    if (I >= 2 * J + 2) return;              // fully-lower tile: dead
    const bool straddle = (I >= 2 * J);      // contains the diagonal

    __shared__ float Ai[2][TR][68];
    __shared__ float Aj[2][TC][68];
    __shared__ float As[TR][68];
    __shared__ float sW[HH * 4];
    __shared__ float sABC[3];
    const int tid = threadIdx.x;
    const int i0 = I * TR, j0 = J * TC;

    // stage row tile (1024 f4), col tile (2048 f4), weights
    for (int t = 0; t < 8; ++t) {
        int flat = tid + 128 * t;            // 0..1023
        int k  = flat >> 9;
        int rr = (flat >> 4) & 31;
        int d4 = (flat & 15) * 4;
        *(float4*)&Ai[k][rr][d4] =
            *(const float4*)&Xc32[(((size_t)(b * 2 + k)) * NN + i0 + rr) * 64 + d4];
    }
    for (int t = 0; t < 16; ++t) {
        int flat = tid + 128 * t;            // 0..2047
        int k  = flat >> 10;
        int rr = (flat >> 4) & 63;
        int d4 = (flat & 15) * 4;
        *(float4*)&Aj[k][rr][d4] =
            *(const float4*)&Xc32[(((size_t)(b * 2 + k)) * NN + j0 + rr) * 64 + d4];
    }
    *(float4*)&sW[tid * 4] = *(const float4*)&wpackf[tid * 4];
    if (tid < 3) sABC[tid] = wpackf[512 + tid];
    __syncthreads();

    const int q = tid & 7;        // row group: rows q + 8*mr
    const int p = tid >> 3;       // col group: cols p + 16*mc

    // gram: acc[k][mr][mc]
    float acc[2][4][4];
#pragma unroll
    for (int k = 0; k < 2; ++k)
        for (int mr = 0; mr < 4; ++mr)
            for (int mc = 0; mc < 4; ++mc) acc[k][mr][mc] = 0.f;

#pragma unroll 2
    for (int d4 = 0; d4 < 64; d4 += 4) {
        float4 ra[2][4], ca[2][4];
#pragma unroll
        for (int k = 0; k < 2; ++k)
#pragma unroll
            for (int m = 0; m < 4; ++m) {
                ra[k][m] = *(const float4*)&Ai[k][q + 8 * m][d4];
                ca[k][m] = *(const float4*)&Aj[k][p + 16 * m][d4];
            }
#pragma unroll
        for (int k = 0; k < 2; ++k)
#pragma unroll
            for (int mr = 0; mr < 4; ++mr)
#pragma unroll
                for (int mc = 0; mc < 4; ++mc)
                    acc[k][mr][mc] += ra[k][mr].x * ca[k][mc].x
                                    + ra[k][mr].y * ca[k][mc].y
                                    + ra[k][mr].z * ca[k][mc].z
                                    + ra[k][mr].w * ca[k][mc].w;
    }

    // gumbel prefetch (latency overlaps MLP loop)
    float2 ge[4][4];
#pragma unroll
    for (int mr = 0; mr < 4; ++mr)
#pragma unroll
        for (int mc = 0; mc < 4; ++mc) {
            int gi = i0 + q + 8 * mr, gj = j0 + p + 16 * mc;
            ge[mr][mc] = *(const float2*)&gumbel[(((size_t)b * NN + gi) * NN + gj) * 2];
        }

    // |z| accumulation: mabs[mr][mc] = sum_c wd_c * |a_c p0 + b_c p1 + beta_c|
    float mabs[4][4];
#pragma unroll
    for (int mr = 0; mr < 4; ++mr)
        for (int mc = 0; mc < 4; ++mc) mabs[mr][mc] = 0.f;

#pragma unroll 4
    for (int cc = 0; cc < HH; ++cc) {
        float4 w = *(const float4*)&sW[4 * cc];   // {a, b, beta, wd}
#pragma unroll
        for (int mr = 0; mr < 4; ++mr)
#pragma unroll
            for (int mc = 0; mc < 4; ++mc) {
                float z = fmaf(acc[1][mr][mc], w.y, fmaf(acc[0][mr][mc], w.x, w.z));
                mabs[mr][mc] = fmaf(fabsf(z), w.w, mabs[mr][mc]);
            }
    }

    const float bd = sm_b2[1] - sm_b2[0];
    const float A = sABC[0], Bl = sABC[1], Cl = sABC[2];

    float mv[4][4];
#pragma unroll
    for (int mr = 0; mr < 4; ++mr)
#pragma unroll
        for (int mc = 0; mc < 4; ++mc) {
            float lin = fmaf(acc[0][mr][mc], A, fmaf(acc[1][mr][mc], Bl, Cl));
            mv[mr][mc] = bd + (ge[mr][mc].y - ge[mr][mc].x)
                       + 0.5f * (lin + mabs[mr][mc]);
        }

    // flag near-threshold upper edges for exact f64 repair
#pragma unroll
    for (int mr = 0; mr < 4; ++mr)
#pragma unroll
        for (int mc = 0; mc < 4; ++mc) {
            int gi = i0 + q + 8 * mr, gj = j0 + p + 16 * mc;
            if (gj > gi && fabsf(mv[mr][mc]) < DELTA) {
                unsigned slot = atomicAdd(counter, 1u);
                if (slot < WCAP)
                    worklist[slot] = ((unsigned)(b * NN + gi)) * NN + (unsigned)gj;
            }
        }

    if (!straddle) {
        // fully-upper tile: rect + transposed rect, coalesced via LDS
#pragma unroll
        for (int mr = 0; mr < 4; ++mr)
#pragma unroll
            for (int mc = 0; mc < 4; ++mc)
                As[q + 8 * mr][p + 16 * mc] = mv[mr][mc] > 0.f ? 1.f : 0.f;
        __syncthreads();
        for (int t = 0; t < 4; ++t) {
            int idx = tid + 128 * t;         // 0..511
            int rr  = idx >> 4;              // 0..31
            int c4  = (idx & 15) * 4;
            float4 v = *(const float4*)&As[rr][c4];
            *(float4*)&out[((size_t)b * NN + i0 + rr) * NN + j0 + c4] = v;
        }
        for (int t = 0; t < 4; ++t) {
            int idx = tid + 128 * t;         // 0..511
            int rr  = idx >> 3;              // 0..63 (col j)
            int c4  = (idx & 7) * 4;         // row base
            float4 v; float* vp = (float*)&v;
#pragma unroll
            for (int u = 0; u < 4; ++u) vp[u] = As[c4 + u][rr];
            *(float4*)&out[((size_t)b * NN + j0 + rr) * NN + i0 + c4] = v;
        }
    } else {
        // diagonal-straddling tile: predicated scatter (upper + mirror + diag zero)
#pragma unroll
        for (int mr = 0; mr < 4; ++mr)
#pragma unroll
            for (int mc = 0; mc < 4; ++mc) {
                int gi = i0 + q + 8 * mr, gj = j0 + p + 16 * mc;
                if (gj > gi) {
                    float v = mv[mr][mc] > 0.f ? 1.f : 0.f;
                    out[((size_t)b * NN + gi) * NN + gj] = v;
                    out[((size_t)b * NN + gj) * NN + gi] = v;
                } else if (gj == gi) {
                    out[((size_t)b * NN + gi) * NN + gj] = 0.f;
                }
            }
    }
}

// k3: exact f64 re-adjudication of flagged edges
__global__ __launch_bounds__(64)
void repair_kernel(const double* __restrict__ Xc64,
                   const double* __restrict__ wpack64,
                   const float* __restrict__ sm_b2,
                   const float* __restrict__ gumbel,
                   float* __restrict__ out,
                   const unsigned* __restrict__ counter,
                   const unsigned* __restrict__ worklist) {
    unsigned n = *counter;
    if (n > WCAP) n = WCAP;
    for (unsigned t = blockIdx.x * blockDim.x + threadIdx.x; t < n;
         t += gridDim.x * blockDim.x) {
        unsigned e = worklist[t];
        int j = e % NN;
        unsigned rr = e / NN;
        int i = rr % NN;
        int b = rr / NN;
        const double* xi0 = &Xc64[(((size_t)(b * 2 + 0)) * NN + i) * 64];
        const double* xj0 = &Xc64[(((size_t)(b * 2 + 0)) * NN + j) * 64];
        const double* xi1 = &Xc64[(((size_t)(b * 2 + 1)) * NN + i) * 64];
        const double* xj1 = &Xc64[(((size_t)(b * 2 + 1)) * NN + j) * 64];
        double p0a = 0, p0b = 0, p1a = 0, p1b = 0;
        for (int d = 0; d < 64; d += 2) {
            p0a = fma(xi0[d],     xj0[d],     p0a);
            p0b = fma(xi0[d + 1], xj0[d + 1], p0b);
            p1a = fma(xi1[d],     xj1[d],     p1a);
            p1b = fma(xi1[d + 1], xj1[d + 1], p1b);
        }
        double p0 = p0a + p0b, p1 = p1a + p1b;
        const float* g = &gumbel[(((size_t)b * NN + i) * NN + j) * 2];
        double mA = ((double)sm_b2[1] - (double)sm_b2[0]) + ((double)g[1] - (double)g[0]);
        double mB = 0.0;
        for (int c = 0; c < HH; c += 2) {
            double2 wab0 = *(const double2*)&wpack64[4 * c];
            double2 wbw0 = *(const double2*)&wpack64[4 * c + 2];
            double2 wab1 = *(const double2*)&wpack64[4 * c + 4];
            double2 wbw1 = *(const double2*)&wpack64[4 * c + 6];
            double t0 = fma(p1, wab0.y, fma(p0, wab0.x, wbw0.x));
            double t1 = fma(p1, wab1.y, fma(p0, wab1.x, wbw1.x));
            t0 = fmax(t0, 0.0); t1 = fmax(t1, 0.0);
            mA = fma(t0, wbw0.y, mA);
            mB = fma(t1, wbw1.y, mB);
        }
        float v = (mA + mB) > 0.0 ? 1.f : 0.f;
        out[((size_t)b * NN + i) * NN + j] = v;
        out[((size_t)b * NN + j) * NN + i] = v;
    }
}

extern "C" void kernel_launch(void* const* d_in, const int* in_sizes, int n_in,
                              void* d_out, int out_size, void* d_ws, size_t ws_size,
                              hipStream_t stream) {
    const float* X      = (const float*)d_in[0];
    const float* ef_w1  = (const float*)d_in[1];
    const float* ef_b1  = (const float*)d_in[2];
    const float* ef_w2  = (const float*)d_in[3];
    const float* ef_b2  = (const float*)d_in[4];
    const float* gate   = (const float*)d_in[5];
    const float* sm_w1  = (const float*)d_in[6];
    const float* sm_b1  = (const float*)d_in[7];
    const float* sm_w2  = (const float*)d_in[8];
    const float* sm_b2  = (const float*)d_in[9];
    const float* gumbel = (const float*)d_in[10];
    float* out = (float*)d_out;

    double*   Xc64     = (double*)d_ws;                     // 196608 doubles
    float*    Xc32     = (float*)(Xc64 + 196608);           // 196608 floats
    double*   wpack64  = (double*)(Xc32 + 196608);          // 512 doubles
    float*    wpackf   = (float*)(wpack64 + 512);           // 512 + 3 (+pad) floats
    unsigned* counter  = (unsigned*)(wpackf + 520);
    unsigned* worklist = counter + 4;                       // WCAP entries

    edgefeat_kernel<<<BB * NN / 2, 256, 0, stream>>>(
        X, ef_w1, ef_b1, ef_w2, ef_b2, gate, sm_w1, sm_b1, sm_w2,
        Xc64, Xc32, wpack64, wpackf, counter);
    dim3 grid(NIT, NJT, BB);
    decide32_kernel<<<grid, 128, 0, stream>>>(Xc32, wpackf, sm_b2, gumbel, out,
                                              counter, worklist);
    repair_kernel<<<64, 64, 0, stream>>>(Xc64, wpack64, sm_b2, gumbel, out,
                                         counter, worklist);
}